// Round 1
// baseline (167.308 us; speedup 1.0000x reference)
//
#include <hip/hip_runtime.h>
#include <hip/hip_bf16.h>
#include <stdint.h>

typedef __bf16 bf16_t;
typedef bf16_t bf16x8 __attribute__((ext_vector_type(8)));
typedef float f32x4 __attribute__((ext_vector_type(4)));

#define DEVI static __device__ __forceinline__

constexpr int NB = 32, CIN = 256, COUT = 256, KNUM = 6, ET = 3, TDIM = 64, VV = 25;
constexpr int NCOL = NB * TDIM * VV;   // 51200 columns (n,t,w)
constexpr int KD   = KNUM * CIN;       // 1536 contraction dim (k,ci)
constexpr long OUT0 = (long)NB * COUT * TDIM * VV;  // 13107200 (x_sum elems)
constexpr int ACNT = ET * VV * VV;     // 1875 (A copy)

// workspace layout
constexpr size_t GT_BYTES   = (size_t)NCOL * KD * 2;        // g, bf16 [col][kc]
constexpr size_t WP_OFF     = GT_BYTES;
constexpr size_t WP_BYTES   = (size_t)COUT * KD * 2;        // Wp, bf16 [c][kc]
constexpr size_t BIAS_OFF   = WP_OFF + WP_BYTES;
constexpr size_t BIAS_BYTES = (size_t)NB * VV * COUT * 4;   // bias [n][w][c] f32
constexpr size_t WS_NEED    = BIAS_OFF + BIAS_BYTES;

// ---------------- prep: Wp permute + bias table + A copy ----------------
__global__ __launch_bounds__(256) void prep_kernel(
    const float* __restrict__ A, const float* __restrict__ Bm,
    const float* __restrict__ lam_p, const float* __restrict__ W,
    const float* __restrict__ bvec, bf16_t* __restrict__ wp2,
    float* __restrict__ biasmat, float* __restrict__ outA)
{
  int idx = blockIdx.x * 256 + threadIdx.x;
  constexpr int S1 = COUT * KD;             // 393216
  constexpr int S2 = S1 + NB * VV * COUT;   // +204800
  constexpr int S3 = S2 + ACNT;
  if (idx < S1) {
    // Wp2[c][k*256+ci] = W[ci][k*256+c]
    int c = idx / KD;
    int r = idx - c * KD;
    int k = r >> 8, ci = r & 255;
    wp2[idx] = (bf16_t)W[ci * KD + (k << 8) + c];
  } else if (idx < S2) {
    // bias[n][w][c] = sum_k b[k*256+c] * S[n,k,w],  S = col-sum of M (lam folded)
    int j = idx - S1;
    int c = j & 255;
    int nw = j >> 8;
    int w = nw % VV;
    int n = nw / VV;
    float lam = lam_p[0];
    float s = 0.f;
    for (int k = 0; k < KNUM; ++k) {
      float sk = 0.f;
      if (k < ET) {
        for (int v = 0; v < VV; ++v) sk += A[(k * VV + v) * VV + w];
      } else {
        for (int v = 0; v < VV; ++v) sk += Bm[(((n * ET) + (k - ET)) * VV + v) * VV + w];
        sk *= lam;
      }
      s += bvec[(k << 8) + c] * sk;
    }
    biasmat[j] = s;
  } else if (idx < S3) {
    int j = idx - S2;
    outA[j] = A[j];   // second tuple output: A passthrough
  }
}

// ---------------- aggregate-first: g[col][kc] = sum_v x*M ----------------
__global__ __launch_bounds__(256) void agg_kernel(
    const float* __restrict__ x, const float* __restrict__ A,
    const float* __restrict__ Bm, const float* __restrict__ lam_p,
    bf16_t* __restrict__ gt)
{
  __shared__ __align__(16) float Mt[KNUM][VV][28];   // [k][w][v], padded to 28
  const int nt = blockIdx.x;          // n*64 + t
  const int n = nt >> 6, t = nt & 63;
  const int tid = threadIdx.x;        // tid == ci
  const float lam = lam_p[0];

  for (int i = tid; i < KNUM * VV * VV; i += 256) {
    int k = i / (VV * VV);
    int r = i - k * VV * VV;
    int v = r / VV;
    int w = r - v * VV;
    float val = (k < ET) ? A[(k * VV + v) * VV + w]
                         : lam * Bm[(((n * ET) + (k - ET)) * VV + v) * VV + w];
    Mt[k][w][v] = val;                // transpose v<->w for contiguous v reads
  }

  float xr[28];
  const float* xp = x + (((long)(n * CIN + tid) * TDIM + t) * VV);
  #pragma unroll
  for (int v = 0; v < VV; ++v) xr[v] = xp[v];
  xr[25] = xr[26] = xr[27] = 0.f;     // pad lanes multiply into garbage Mt pad -> 0
  __syncthreads();

  bf16_t* gb = gt + (long)nt * (VV * KD) + tid;
  #pragma unroll
  for (int k = 0; k < KNUM; ++k) {
    #pragma unroll
    for (int w = 0; w < VV; ++w) {
      const f32x4* m4 = (const f32x4*)&Mt[k][w][0];
      float acc = 0.f;
      #pragma unroll
      for (int q = 0; q < 7; ++q) {
        f32x4 mv = m4[q];
        acc += xr[q*4+0]*mv[0] + xr[q*4+1]*mv[1]
             + xr[q*4+2]*mv[2] + xr[q*4+3]*mv[3];
      }
      gb[(long)w * KD + (k << 8)] = (bf16_t)acc;
    }
  }
}

// ---------------- MFMA GEMM: out = Wp^T(256x1536) @ g(1536x51200) ----------------
DEVI void gload16(const void* g, void* l) {
  __builtin_amdgcn_global_load_lds((const __attribute__((address_space(1))) void*)g,
                                   (__attribute__((address_space(3))) void*)l, 16, 0, 0);
}

__global__ __launch_bounds__(512) void gemm_kernel(
    const bf16_t* __restrict__ wp2, const bf16_t* __restrict__ gt,
    const float* __restrict__ biasmat, float* __restrict__ out)
{
  // BM=256 (all of c), BN=128 (cols), BK=64. 8 waves in 4(M)x2(N), 64x64 each.
  __shared__ bf16_t As[256 * 64];   // [m][kk] row-major, K-contiguous
  __shared__ bf16_t Bs[128 * 64];   // [nl][kk]
  const int tid = threadIdx.x;
  const int wv = tid >> 6, ln = tid & 63;
  const int col0 = blockIdx.x * 128;
  const int m_base = (wv >> 1) * 64;
  const int n_base = (wv & 1) * 64;

  f32x4 acc[4][4] = {};

  const int itemA0 = wv * 256 + ln;   // +q*64, q<4  (32KB As)
  const int itemB0 = wv * 128 + ln;   // +q*64, q<2  (16KB Bs)

  for (int k0 = 0; k0 < KD; k0 += 64) {
    #pragma unroll
    for (int q = 0; q < 4; ++q) {
      int it = itemA0 + q * 64;
      gload16(wp2 + ((it >> 3) * KD + k0 + (it & 7) * 8), As + it * 8);
    }
    #pragma unroll
    for (int q = 0; q < 2; ++q) {
      int it = itemB0 + q * 64;
      gload16(gt + ((long)(col0 + (it >> 3)) * KD + k0 + (it & 7) * 8), Bs + it * 8);
    }
    __syncthreads();   // drains vmcnt(0) -> tiles visible

    #pragma unroll
    for (int kk = 0; kk < 2; ++kk) {
      const int ko = ((ln >> 4) << 3) + kk * 32;
      bf16x8 af[4], bfr[4];
      #pragma unroll
      for (int i = 0; i < 4; ++i)
        af[i] = *(const bf16x8*)&As[(m_base + i * 16 + (ln & 15)) * 64 + ko];
      #pragma unroll
      for (int j = 0; j < 4; ++j)
        bfr[j] = *(const bf16x8*)&Bs[(n_base + j * 16 + (ln & 15)) * 64 + ko];
      #pragma unroll
      for (int i = 0; i < 4; ++i)
        #pragma unroll
        for (int j = 0; j < 4; ++j)
          acc[i][j] = __builtin_amdgcn_mfma_f32_16x16x32_bf16(af[i], bfr[j], acc[i][j], 0, 0, 0);
    }
    __syncthreads();   // all waves done reading before next stage overwrites
  }

  // epilogue: C/D map col=lane&15, row=(lane>>4)*4+reg  [m89-verified]
  #pragma unroll
  for (int j = 0; j < 4; ++j) {
    int col = col0 + n_base + j * 16 + (ln & 15);
    int n = col / 1600;           // 1600 = T*V
    int tw = col - n * 1600;
    int w = tw % 25;
    float* ob = out + (long)n * 409600 + tw;          // 409600 = 256*1600
    const float* brow = biasmat + (n * 25 + w) * 256;
    #pragma unroll
    for (int i = 0; i < 4; ++i) {
      int mb = m_base + i * 16 + ((ln >> 4) << 2);
      #pragma unroll
      for (int r = 0; r < 4; ++r) {
        int m = mb + r;
        ob[(long)m * 1600] = acc[i][j][r] + brow[m];
      }
    }
  }
}

// ---------------- ws-free fp32 fallback (insurance) ----------------
__global__ __launch_bounds__(256) void fallback_kernel(
    const float* __restrict__ x, const float* __restrict__ A,
    const float* __restrict__ Bm, const float* __restrict__ lam_p,
    const float* __restrict__ W, const float* __restrict__ bvec,
    float* __restrict__ out)
{
  __shared__ __align__(16) float xs[CIN][28];
  __shared__ __align__(16) float Ms[KNUM][VV][28];   // [k][v][w] padded
  const int nt = blockIdx.x;
  const int n = nt >> 6, t = nt & 63;
  const int tid = threadIdx.x;
  const float lam = lam_p[0];

  const float* xp = x + (((long)(n * CIN + tid) * TDIM + t) * VV);
  #pragma unroll
  for (int v = 0; v < VV; ++v) xs[tid][v] = xp[v];
  xs[tid][25] = xs[tid][26] = xs[tid][27] = 0.f;
  for (int i = tid; i < KNUM * VV * VV; i += 256) {
    int k = i / (VV * VV);
    int r = i - k * VV * VV;
    int v = r / VV;
    int w = r - v * VV;
    Ms[k][v][w] = (k < ET) ? A[(k * VV + v) * VV + w]
                           : lam * Bm[(((n * ET) + (k - ET)) * VV + v) * VV + w];
    if (w == 24) { Ms[k][v][25] = Ms[k][v][26] = Ms[k][v][27] = 0.f; }
  }
  __syncthreads();

  float oacc[28] = {};
  for (int k = 0; k < KNUM; ++k) {
    float yv[28];
    float bv = bvec[(k << 8) + tid];
    #pragma unroll
    for (int v = 0; v < 28; ++v) yv[v] = 0.f;
    for (int ci = 0; ci < CIN; ++ci) {
      float wl = W[ci * KD + (k << 8) + tid];
      const f32x4* x4 = (const f32x4*)&xs[ci][0];
      #pragma unroll
      for (int q = 0; q < 7; ++q) {
        f32x4 xv = x4[q];
        yv[q*4+0] += wl*xv[0]; yv[q*4+1] += wl*xv[1];
        yv[q*4+2] += wl*xv[2]; yv[q*4+3] += wl*xv[3];
      }
    }
    #pragma unroll
    for (int v = 0; v < VV; ++v) {
      float yvv = yv[v] + bv;
      const f32x4* m4 = (const f32x4*)&Ms[k][v][0];
      #pragma unroll
      for (int q = 0; q < 7; ++q) {
        f32x4 mv = m4[q];
        oacc[q*4+0] += yvv*mv[0]; oacc[q*4+1] += yvv*mv[1];
        oacc[q*4+2] += yvv*mv[2]; oacc[q*4+3] += yvv*mv[3];
      }
    }
  }
  float* op = out + (((long)(n * COUT + tid) * TDIM + t) * VV);
  #pragma unroll
  for (int w = 0; w < VV; ++w) op[w] = oacc[w];
}

__global__ void copyA_kernel(const float* __restrict__ A, float* __restrict__ outA) {
  int i = blockIdx.x * 256 + threadIdx.x;
  if (i < ACNT) outA[i] = A[i];
}

extern "C" void kernel_launch(void* const* d_in, const int* in_sizes, int n_in,
                              void* d_out, int out_size, void* d_ws, size_t ws_size,
                              hipStream_t stream) {
  const float* x   = (const float*)d_in[0];
  const float* A   = (const float*)d_in[1];
  const float* Bm  = (const float*)d_in[2];
  const float* lam = (const float*)d_in[3];
  const float* W   = (const float*)d_in[4];
  const float* bv  = (const float*)d_in[5];
  float* out = (float*)d_out;

  if (d_ws != nullptr && ws_size >= WS_NEED) {
    bf16_t* gt      = (bf16_t*)d_ws;
    bf16_t* wp2     = (bf16_t*)((char*)d_ws + WP_OFF);
    float*  biasmat = (float*)((char*)d_ws + BIAS_OFF);
    constexpr int PREP_ITEMS = COUT * KD + NB * VV * COUT + ACNT;
    prep_kernel<<<(PREP_ITEMS + 255) / 256, 256, 0, stream>>>(A, Bm, lam, W, bv, wp2, biasmat, out + OUT0);
    agg_kernel<<<NB * TDIM, 256, 0, stream>>>(x, A, Bm, lam, gt);
    gemm_kernel<<<NCOL / 128, 512, 0, stream>>>(wp2, gt, biasmat, out);
  } else {
    fallback_kernel<<<NB * TDIM, 256, 0, stream>>>(x, A, Bm, lam, W, bv, out);
    copyA_kernel<<<(ACNT + 255) / 256, 256, 0, stream>>>(A, out + OUT0);
  }
}

// Round 2
// 145.143 us; speedup vs baseline: 1.1527x; 1.1527x over previous
//
#include <hip/hip_runtime.h>
#include <hip/hip_bf16.h>
#include <stdint.h>

typedef __bf16 bf16_t;
typedef bf16_t bf16x8 __attribute__((ext_vector_type(8)));
typedef float f32x4 __attribute__((ext_vector_type(4)));

#define DEVI static __device__ __forceinline__

constexpr int NB = 32, CIN = 256, COUT = 256, KNUM = 6, ET = 3, TDIM = 64, VV = 25;
constexpr int NCOL = NB * TDIM * VV;   // 51200 columns (n,t,w)
constexpr int KD   = KNUM * CIN;       // 1536 contraction dim (k,ci)
constexpr long OUT0 = (long)NB * COUT * TDIM * VV;  // 13107200 (x_sum elems)
constexpr int ACNT = ET * VV * VV;     // 1875 (A copy)

// workspace layout
constexpr size_t GT_BYTES   = (size_t)NCOL * KD * 2;        // g, bf16 [col][kc]
constexpr size_t WP_OFF     = GT_BYTES;
constexpr size_t WP_BYTES   = (size_t)COUT * KD * 2;        // Wp, bf16 [c][kc]
constexpr size_t BIAS_OFF   = WP_OFF + WP_BYTES;
constexpr size_t BIAS_BYTES = (size_t)NB * VV * COUT * 4;   // bias [n][w][c] f32
constexpr size_t WS_NEED    = BIAS_OFF + BIAS_BYTES;

// ---------------- prep: Wp permute + bias table + A copy ----------------
__global__ __launch_bounds__(256) void prep_kernel(
    const float* __restrict__ A, const float* __restrict__ Bm,
    const float* __restrict__ lam_p, const float* __restrict__ W,
    const float* __restrict__ bvec, bf16_t* __restrict__ wp2,
    float* __restrict__ biasmat, float* __restrict__ outA)
{
  int idx = blockIdx.x * 256 + threadIdx.x;
  constexpr int S1 = COUT * KD;             // 393216
  constexpr int S2 = S1 + NB * VV * COUT;   // +204800
  constexpr int S3 = S2 + ACNT;
  if (idx < S1) {
    // Wp2[c][k*256+ci] = W[ci][k*256+c]
    int c = idx / KD;
    int r = idx - c * KD;
    int k = r >> 8, ci = r & 255;
    wp2[idx] = (bf16_t)W[ci * KD + (k << 8) + c];
  } else if (idx < S2) {
    // bias[n][w][c] = sum_k b[k*256+c] * S[n,k,w],  S = col-sum of M (lam folded)
    int j = idx - S1;
    int c = j & 255;
    int nw = j >> 8;
    int w = nw % VV;
    int n = nw / VV;
    float lam = lam_p[0];
    float s = 0.f;
    for (int k = 0; k < KNUM; ++k) {
      float sk = 0.f;
      if (k < ET) {
        for (int v = 0; v < VV; ++v) sk += A[(k * VV + v) * VV + w];
      } else {
        for (int v = 0; v < VV; ++v) sk += Bm[(((n * ET) + (k - ET)) * VV + v) * VV + w];
        sk *= lam;
      }
      s += bvec[(k << 8) + c] * sk;
    }
    biasmat[j] = s;
  } else if (idx < S3) {
    int j = idx - S2;
    outA[j] = A[j];   // second tuple output: A passthrough
  }
}

// ---------------- aggregate-first: g[col][kc] = sum_v x*M ----------------
// 4 t-values per thread: each 7xds_read_b128 M-row feeds 100 FMAs (was 25).
__global__ __launch_bounds__(256) void agg_kernel(
    const float* __restrict__ x, const float* __restrict__ A,
    const float* __restrict__ Bm, const float* __restrict__ lam_p,
    bf16_t* __restrict__ gt)
{
  __shared__ __align__(16) float Mt[KNUM][VV][28];   // [k][w][v], padded to 28
  const int b = blockIdx.x;           // n*16 + t-group
  const int n = b >> 4, t0 = (b & 15) << 2;
  const int tid = threadIdx.x;        // tid == ci
  const float lam = lam_p[0];

  for (int i = tid; i < KNUM * VV * VV; i += 256) {
    int k = i / (VV * VV);
    int r = i - k * VV * VV;
    int v = r / VV;
    int w = r - v * VV;
    float val = (k < ET) ? A[(k * VV + v) * VV + w]
                         : lam * Bm[(((n * ET) + (k - ET)) * VV + v) * VV + w];
    Mt[k][w][v] = val;                // transpose v<->w for contiguous v reads
  }

  // 100 contiguous floats: x[n, ci, t0..t0+3, 0..24], 16B-aligned (t0%4==0)
  f32x4 xv[25];
  const f32x4* xp4 = (const f32x4*)(x + (((long)(n * CIN + tid) * TDIM + t0) * VV));
  #pragma unroll
  for (int q = 0; q < 25; ++q) xv[q] = xp4[q];
  __syncthreads();

  const long colbase = (long)(n * TDIM + t0) * VV;
  #pragma unroll 1
  for (int k = 0; k < KNUM; ++k) {
    bf16_t* gk = gt + colbase * KD + (k << 8) + tid;
    #pragma unroll 1
    for (int w = 0; w < VV; ++w) {
      const f32x4* m4 = (const f32x4*)&Mt[k][w][0];
      f32x4 m[7];
      #pragma unroll
      for (int q = 0; q < 7; ++q) m[q] = m4[q];   // m[6] tail lanes unused
      float a0 = 0.f, a1 = 0.f, a2 = 0.f, a3 = 0.f;
      #pragma unroll
      for (int v = 0; v < VV; ++v) {
        float mv = m[v >> 2][v & 3];
        a0 += xv[v >> 2][v & 3] * mv;
        a1 += xv[(25 + v) >> 2][(25 + v) & 3] * mv;
        a2 += xv[(50 + v) >> 2][(50 + v) & 3] * mv;
        a3 += xv[(75 + v) >> 2][(75 + v) & 3] * mv;
      }
      bf16_t* gw = gk + (long)w * KD;
      gw[0]            = (bf16_t)a0;
      gw[25 * KD]      = (bf16_t)a1;
      gw[50 * KD]      = (bf16_t)a2;
      gw[75 * KD]      = (bf16_t)a3;
    }
  }
}

// ---------------- MFMA GEMM: out = Wp^T(256x1536) @ g(1536x51200) ----------------
DEVI void gload16(const void* g, void* l) {
  __builtin_amdgcn_global_load_lds((const __attribute__((address_space(1))) void*)g,
                                   (__attribute__((address_space(3))) void*)l, 16, 0, 0);
}

__global__ __launch_bounds__(512) void gemm_kernel(
    const bf16_t* __restrict__ wp2, const bf16_t* __restrict__ gt,
    const float* __restrict__ biasmat, float* __restrict__ out)
{
  // BM=256 (all of c), BN=128 (cols), BK=64. 8 waves in 4(M)x2(N), 64x64 each.
  __shared__ bf16_t As[256 * 64];   // [m][kk] row-major, K-contiguous
  __shared__ bf16_t Bs[128 * 64];   // [nl][kk]
  const int tid = threadIdx.x;
  const int wv = tid >> 6, ln = tid & 63;
  const int col0 = blockIdx.x * 128;
  const int m_base = (wv >> 1) * 64;
  const int n_base = (wv & 1) * 64;

  f32x4 acc[4][4] = {};

  const int itemA0 = wv * 256 + ln;   // +q*64, q<4  (32KB As)
  const int itemB0 = wv * 128 + ln;   // +q*64, q<2  (16KB Bs)

  for (int k0 = 0; k0 < KD; k0 += 64) {
    #pragma unroll
    for (int q = 0; q < 4; ++q) {
      int it = itemA0 + q * 64;
      gload16(wp2 + ((it >> 3) * KD + k0 + (it & 7) * 8), As + it * 8);
    }
    #pragma unroll
    for (int q = 0; q < 2; ++q) {
      int it = itemB0 + q * 64;
      gload16(gt + ((long)(col0 + (it >> 3)) * KD + k0 + (it & 7) * 8), Bs + it * 8);
    }
    __syncthreads();   // drains vmcnt(0) -> tiles visible

    #pragma unroll
    for (int kk = 0; kk < 2; ++kk) {
      const int ko = ((ln >> 4) << 3) + kk * 32;
      bf16x8 af[4], bfr[4];
      #pragma unroll
      for (int i = 0; i < 4; ++i)
        af[i] = *(const bf16x8*)&As[(m_base + i * 16 + (ln & 15)) * 64 + ko];
      #pragma unroll
      for (int j = 0; j < 4; ++j)
        bfr[j] = *(const bf16x8*)&Bs[(n_base + j * 16 + (ln & 15)) * 64 + ko];
      #pragma unroll
      for (int i = 0; i < 4; ++i)
        #pragma unroll
        for (int j = 0; j < 4; ++j)
          acc[i][j] = __builtin_amdgcn_mfma_f32_16x16x32_bf16(af[i], bfr[j], acc[i][j], 0, 0, 0);
    }
    __syncthreads();   // all waves done reading before next stage overwrites
  }

  // epilogue: C/D map col=lane&15, row=(lane>>4)*4+reg  [m89-verified]
  #pragma unroll
  for (int j = 0; j < 4; ++j) {
    int col = col0 + n_base + j * 16 + (ln & 15);
    int n = col / 1600;           // 1600 = T*V
    int tw = col - n * 1600;
    int w = tw % 25;
    float* ob = out + (long)n * 409600 + tw;          // 409600 = 256*1600
    const float* brow = biasmat + (n * 25 + w) * 256;
    #pragma unroll
    for (int i = 0; i < 4; ++i) {
      int mb = m_base + i * 16 + ((ln >> 4) << 2);
      #pragma unroll
      for (int r = 0; r < 4; ++r) {
        int m = mb + r;
        ob[(long)m * 1600] = acc[i][j][r] + brow[m];
      }
    }
  }
}

// ---------------- ws-free fp32 fallback (insurance) ----------------
__global__ __launch_bounds__(256) void fallback_kernel(
    const float* __restrict__ x, const float* __restrict__ A,
    const float* __restrict__ Bm, const float* __restrict__ lam_p,
    const float* __restrict__ W, const float* __restrict__ bvec,
    float* __restrict__ out)
{
  __shared__ __align__(16) float xs[CIN][28];
  __shared__ __align__(16) float Ms[KNUM][VV][28];   // [k][v][w] padded
  const int nt = blockIdx.x;
  const int n = nt >> 6, t = nt & 63;
  const int tid = threadIdx.x;
  const float lam = lam_p[0];

  const float* xp = x + (((long)(n * CIN + tid) * TDIM + t) * VV);
  #pragma unroll
  for (int v = 0; v < VV; ++v) xs[tid][v] = xp[v];
  xs[tid][25] = xs[tid][26] = xs[tid][27] = 0.f;
  for (int i = tid; i < KNUM * VV * VV; i += 256) {
    int k = i / (VV * VV);
    int r = i - k * VV * VV;
    int v = r / VV;
    int w = r - v * VV;
    Ms[k][v][w] = (k < ET) ? A[(k * VV + v) * VV + w]
                           : lam * Bm[(((n * ET) + (k - ET)) * VV + v) * VV + w];
    if (w == 24) { Ms[k][v][25] = Ms[k][v][26] = Ms[k][v][27] = 0.f; }
  }
  __syncthreads();

  float oacc[28] = {};
  for (int k = 0; k < KNUM; ++k) {
    float yv[28];
    float bv = bvec[(k << 8) + tid];
    #pragma unroll
    for (int v = 0; v < 28; ++v) yv[v] = 0.f;
    for (int ci = 0; ci < CIN; ++ci) {
      float wl = W[ci * KD + (k << 8) + tid];
      const f32x4* x4 = (const f32x4*)&xs[ci][0];
      #pragma unroll
      for (int q = 0; q < 7; ++q) {
        f32x4 xv = x4[q];
        yv[q*4+0] += wl*xv[0]; yv[q*4+1] += wl*xv[1];
        yv[q*4+2] += wl*xv[2]; yv[q*4+3] += wl*xv[3];
      }
    }
    #pragma unroll
    for (int v = 0; v < VV; ++v) {
      float yvv = yv[v] + bv;
      const f32x4* m4 = (const f32x4*)&Ms[k][v][0];
      #pragma unroll
      for (int q = 0; q < 7; ++q) {
        f32x4 mv = m4[q];
        oacc[q*4+0] += yvv*mv[0]; oacc[q*4+1] += yvv*mv[1];
        oacc[q*4+2] += yvv*mv[2]; oacc[q*4+3] += yvv*mv[3];
      }
    }
  }
  float* op = out + (((long)(n * COUT + tid) * TDIM + t) * VV);
  #pragma unroll
  for (int w = 0; w < VV; ++w) op[w] = oacc[w];
}

__global__ void copyA_kernel(const float* __restrict__ A, float* __restrict__ outA) {
  int i = blockIdx.x * 256 + threadIdx.x;
  if (i < ACNT) outA[i] = A[i];
}

extern "C" void kernel_launch(void* const* d_in, const int* in_sizes, int n_in,
                              void* d_out, int out_size, void* d_ws, size_t ws_size,
                              hipStream_t stream) {
  const float* x   = (const float*)d_in[0];
  const float* A   = (const float*)d_in[1];
  const float* Bm  = (const float*)d_in[2];
  const float* lam = (const float*)d_in[3];
  const float* W   = (const float*)d_in[4];
  const float* bv  = (const float*)d_in[5];
  float* out = (float*)d_out;

  if (d_ws != nullptr && ws_size >= WS_NEED) {
    bf16_t* gt      = (bf16_t*)d_ws;
    bf16_t* wp2     = (bf16_t*)((char*)d_ws + WP_OFF);
    float*  biasmat = (float*)((char*)d_ws + BIAS_OFF);
    constexpr int PREP_ITEMS = COUT * KD + NB * VV * COUT + ACNT;
    prep_kernel<<<(PREP_ITEMS + 255) / 256, 256, 0, stream>>>(A, Bm, lam, W, bv, wp2, biasmat, out + OUT0);
    agg_kernel<<<NB * TDIM / 4, 256, 0, stream>>>(x, A, Bm, lam, gt);
    gemm_kernel<<<NCOL / 128, 512, 0, stream>>>(wp2, gt, biasmat, out);
  } else {
    fallback_kernel<<<NB * TDIM, 256, 0, stream>>>(x, A, Bm, lam, W, bv, out);
    copyA_kernel<<<(ACNT + 255) / 256, 256, 0, stream>>>(A, out + OUT0);
  }
}